// Round 1
// baseline (1028.466 us; speedup 1.0000x reference)
//
#include <hip/hip_runtime.h>
#include <hip/hip_bf16.h>

constexpr int NN = 50000;
constexpr int NE = 1600000;
constexpr int DI = 512;
constexpr int DH = 256;
constexpr int DO = 64;

// ---------------- CSR build: histogram -> scan -> scatter ----------------

__global__ void k_hist(const int* __restrict__ rows, int* __restrict__ counts, int E) {
    int i = blockIdx.x * blockDim.x + threadIdx.x;
    int stride = gridDim.x * blockDim.x;
    for (; i < E; i += stride) atomicAdd(&counts[rows[i]], 1);
}

__global__ __launch_bounds__(1024) void k_scan(const int* __restrict__ counts,
                                               int* __restrict__ row_ptr,
                                               int* __restrict__ cursor, int n) {
    const int C = (n + 1023) / 1024;   // 49 rows per thread
    int t = threadIdx.x;
    int lo = t * C;
    int hi = min(lo + C, n);
    int s = 0;
    for (int i = lo; i < hi; ++i) s += counts[i];
    __shared__ int buf[1024];
    buf[t] = s;
    __syncthreads();
    // Hillis-Steele inclusive scan over 1024 partials
    for (int off = 1; off < 1024; off <<= 1) {
        int v = (t >= off) ? buf[t - off] : 0;
        __syncthreads();
        buf[t] += v;
        __syncthreads();
    }
    int excl = buf[t] - s;             // exclusive prefix of this thread's chunk
    for (int i = lo; i < hi; ++i) {
        row_ptr[i] = excl;
        cursor[i]  = excl;
        excl += counts[i];
    }
    if (t == 1023) row_ptr[n] = buf[1023];
}

__global__ void k_scatter(const int* __restrict__ rows, const int* __restrict__ cols,
                          const float* __restrict__ vals, int* __restrict__ cursor,
                          int* __restrict__ sc, float* __restrict__ sv, int E) {
    int i = blockIdx.x * blockDim.x + threadIdx.x;
    int stride = gridDim.x * blockDim.x;
    for (; i < E; i += stride) {
        int r = rows[i];
        int p = atomicAdd(&cursor[r], 1);
        sc[p] = cols[i];
        sv[p] = vals[i];
    }
}

// ---------------- GEMM1: h1 = X @ W1 + b1  (fp32 compute, bf16 out) ----------------
// BM=64 BN=64 BK=32, 256 threads, 4x4 per thread.

__global__ __launch_bounds__(256) void k_gemm1(const float* __restrict__ X,
                                               const float* __restrict__ W,
                                               const float* __restrict__ B,
                                               __hip_bfloat16* __restrict__ H) {
    __shared__ float As[64][33];   // +1 pad: reads land 2-way max (free)
    __shared__ float Bs[32][64];
    const int bm = blockIdx.y * 64;
    const int bn = blockIdx.x * 64;
    const int tid = threadIdx.x;
    const int tx = tid & 15, ty = tid >> 4;
    const int ai = tid >> 2;            // 0..63 row in tile
    const int ak = (tid & 3) * 8;       // 0,8,16,24
    const int bk = tid >> 3;            // 0..31
    const int bj = (tid & 7) * 8;       // 0..56

    float acc[4][4] = {};

    for (int kt = 0; kt < DI; kt += 32) {
        // A tile 64x32
        {
            int gr = bm + ai;
            float4 v0 = {0, 0, 0, 0}, v1 = {0, 0, 0, 0};
            if (gr < NN) {
                const float* s = X + (size_t)gr * DI + kt + ak;
                v0 = *(const float4*)s;
                v1 = *(const float4*)(s + 4);
            }
            As[ai][ak + 0] = v0.x; As[ai][ak + 1] = v0.y;
            As[ai][ak + 2] = v0.z; As[ai][ak + 3] = v0.w;
            As[ai][ak + 4] = v1.x; As[ai][ak + 5] = v1.y;
            As[ai][ak + 6] = v1.z; As[ai][ak + 7] = v1.w;
        }
        // B tile 32x64
        {
            const float* s = W + (size_t)(kt + bk) * DH + bn + bj;
            float4 v0 = *(const float4*)s;
            float4 v1 = *(const float4*)(s + 4);
            *(float4*)&Bs[bk][bj]     = v0;
            *(float4*)&Bs[bk][bj + 4] = v1;
        }
        __syncthreads();
        #pragma unroll
        for (int kk = 0; kk < 32; ++kk) {
            float a0 = As[ty * 4 + 0][kk];
            float a1 = As[ty * 4 + 1][kk];
            float a2 = As[ty * 4 + 2][kk];
            float a3 = As[ty * 4 + 3][kk];
            float4 b4 = *(float4*)&Bs[kk][tx * 4];
            acc[0][0] += a0 * b4.x; acc[0][1] += a0 * b4.y; acc[0][2] += a0 * b4.z; acc[0][3] += a0 * b4.w;
            acc[1][0] += a1 * b4.x; acc[1][1] += a1 * b4.y; acc[1][2] += a1 * b4.z; acc[1][3] += a1 * b4.w;
            acc[2][0] += a2 * b4.x; acc[2][1] += a2 * b4.y; acc[2][2] += a2 * b4.z; acc[2][3] += a2 * b4.w;
            acc[3][0] += a3 * b4.x; acc[3][1] += a3 * b4.y; acc[3][2] += a3 * b4.z; acc[3][3] += a3 * b4.w;
        }
        __syncthreads();
    }

    #pragma unroll
    for (int u = 0; u < 4; ++u) {
        int r = bm + ty * 4 + u;
        if (r >= NN) continue;
        #pragma unroll
        for (int v = 0; v < 4; ++v) {
            int c = bn + tx * 4 + v;
            H[(size_t)r * DH + c] = __float2bfloat16(acc[u][v] + B[c]);
        }
    }
}

// ---------------- SpMM1 + ReLU: h1b = relu(A @ h1) ----------------
// one block (256 thr) per row; thread d owns dim d; bf16 gather, fp32 accum.

__global__ __launch_bounds__(256) void k_spmm_relu(const int* __restrict__ rp,
                                                   const int* __restrict__ sc,
                                                   const float* __restrict__ sv,
                                                   const __hip_bfloat16* __restrict__ H,
                                                   __hip_bfloat16* __restrict__ O) {
    int r = blockIdx.x;
    int d = threadIdx.x;
    int s = rp[r], e = rp[r + 1];
    float acc = 0.f;
    for (int i = s; i < e; ++i) {
        float v = sv[i];
        size_t c = (size_t)sc[i] * DH;
        acc += v * __bfloat162float(H[c + d]);
    }
    acc = fmaxf(acc, 0.f);
    O[(size_t)r * DH + d] = __float2bfloat16(acc);
}

// ---------------- GEMM2: h2 = h1b @ W2 + b2 (bf16 in/out, fp32 accum) ----------------
// 4 rows per 256-thread block; thread (rr, j).

__global__ __launch_bounds__(256) void k_gemm2(const __hip_bfloat16* __restrict__ HB,
                                               const float* __restrict__ W,
                                               const float* __restrict__ B,
                                               __hip_bfloat16* __restrict__ H2) {
    __shared__ float hs[4][DH];
    int r0 = blockIdx.x * 4;
    int tid = threadIdx.x;
    for (int i = tid; i < 4 * DH; i += 256) {
        int rr = i >> 8, k = i & 255;
        int r = r0 + rr;
        hs[rr][k] = (r < NN) ? __bfloat162float(HB[(size_t)r * DH + k]) : 0.f;
    }
    __syncthreads();
    int rr = tid >> 6;
    int j  = tid & 63;
    float acc = B[j];
    #pragma unroll 8
    for (int k = 0; k < DH; ++k) acc += hs[rr][k] * W[k * DO + j];
    int r = r0 + rr;
    if (r < NN) H2[(size_t)r * DO + j] = __float2bfloat16(acc);
}

// ---------------- SpMM2: out = A @ h2 (fp32 out) ----------------
// 4 rows per block (one 64-lane wave per row).

__global__ __launch_bounds__(256) void k_spmm_out(const int* __restrict__ rp,
                                                  const int* __restrict__ sc,
                                                  const float* __restrict__ sv,
                                                  const __hip_bfloat16* __restrict__ H2,
                                                  float* __restrict__ OUT) {
    int r = blockIdx.x * 4 + (threadIdx.x >> 6);
    int d = threadIdx.x & 63;
    if (r >= NN) return;
    int s = rp[r], e = rp[r + 1];
    float acc = 0.f;
    for (int i = s; i < e; ++i) {
        acc += sv[i] * __bfloat162float(H2[(size_t)sc[i] * DO + d]);
    }
    OUT[(size_t)r * DO + d] = acc;
}

// ---------------- launch ----------------

extern "C" void kernel_launch(void* const* d_in, const int* in_sizes, int n_in,
                              void* d_out, int out_size, void* d_ws, size_t ws_size,
                              hipStream_t stream) {
    const float* x  = (const float*)d_in[0];
    const int*   er = (const int*)d_in[1];
    const int*   ec = (const int*)d_in[2];
    const float* ev = (const float*)d_in[3];
    const float* W1 = (const float*)d_in[4];
    const float* b1 = (const float*)d_in[5];
    const float* W2 = (const float*)d_in[6];
    const float* b2 = (const float*)d_in[7];
    float* out = (float*)d_out;

    char* ws = (char*)d_ws;
    __hip_bfloat16* h1  = (__hip_bfloat16*)ws; ws += (size_t)NN * DH * 2;  // 25.6 MB
    __hip_bfloat16* h1b = (__hip_bfloat16*)ws; ws += (size_t)NN * DH * 2;  // 25.6 MB
    __hip_bfloat16* h2  = (__hip_bfloat16*)ws; ws += (size_t)NN * DO * 2;  //  6.4 MB
    int*   sc  = (int*)ws;   ws += (size_t)NE * 4;                          //  6.4 MB
    float* sv  = (float*)ws; ws += (size_t)NE * 4;                          //  6.4 MB
    int* counts = (int*)ws;  ws += ((size_t)NN * 4 + 255) & ~(size_t)255;
    int* rp     = (int*)ws;  ws += ((size_t)(NN + 1) * 4 + 255) & ~(size_t)255;
    int* cur    = (int*)ws;  ws += ((size_t)NN * 4 + 255) & ~(size_t)255;

    hipMemsetAsync(counts, 0, (size_t)NN * 4, stream);
    k_hist<<<2048, 256, 0, stream>>>(er, counts, NE);
    k_scan<<<1, 1024, 0, stream>>>(counts, rp, cur, NN);
    k_scatter<<<2048, 256, 0, stream>>>(er, ec, ev, cur, sc, sv, NE);

    dim3 g1(DH / 64, (NN + 63) / 64);
    k_gemm1<<<g1, 256, 0, stream>>>(x, W1, b1, h1);
    k_spmm_relu<<<NN, 256, 0, stream>>>(rp, sc, sv, h1, h1b);
    k_gemm2<<<(NN + 3) / 4, 256, 0, stream>>>(h1b, W2, b2, h2);
    k_spmm_out<<<(NN + 3) / 4, 256, 0, stream>>>(rp, sc, sv, h2, out);
}

// Round 2
// 640.396 us; speedup vs baseline: 1.6060x; 1.6060x over previous
//
#include <hip/hip_runtime.h>
#include <hip/hip_bf16.h>

constexpr int NN = 50000;
constexpr int NE = 1600000;
constexpr int DI = 512;
constexpr int DH = 256;
constexpr int DO = 64;

typedef __attribute__((ext_vector_type(8))) short short8;
typedef __attribute__((ext_vector_type(4))) float f32x4;

__device__ inline ushort f2b(float f) {          // fp32 -> bf16 bits, RNE
    uint u = __float_as_uint(f);
    u += 0x7fffu + ((u >> 16) & 1u);
    return (ushort)(u >> 16);
}
__device__ inline float b2f(ushort u) {          // bf16 bits -> fp32
    return __uint_as_float((uint)u << 16);
}

// ---------------- CSR build: histogram -> scan -> scatter ----------------

__global__ void k_hist(const int* __restrict__ rows, int* __restrict__ counts, int E) {
    int i = blockIdx.x * blockDim.x + threadIdx.x;
    int stride = gridDim.x * blockDim.x;
    for (; i < E; i += stride) atomicAdd(&counts[rows[i]], 1);
}

__global__ __launch_bounds__(1024) void k_scan(const int* __restrict__ counts,
                                               int* __restrict__ row_ptr,
                                               int* __restrict__ cursor, int n) {
    const int C = (n + 1023) / 1024;
    int t = threadIdx.x;
    int lo = t * C;
    int hi = min(lo + C, n);
    int s = 0;
    for (int i = lo; i < hi; ++i) s += counts[i];
    __shared__ int buf[1024];
    buf[t] = s;
    __syncthreads();
    for (int off = 1; off < 1024; off <<= 1) {
        int v = (t >= off) ? buf[t - off] : 0;
        __syncthreads();
        buf[t] += v;
        __syncthreads();
    }
    int excl = buf[t] - s;
    for (int i = lo; i < hi; ++i) {
        row_ptr[i] = excl;
        cursor[i]  = excl;
        excl += counts[i];
    }
    if (t == 1023) row_ptr[n] = buf[1023];
}

__global__ void k_scatter(const int* __restrict__ rows, const int* __restrict__ cols,
                          const float* __restrict__ vals, int* __restrict__ cursor,
                          int2* __restrict__ ev8, int E) {
    int i = blockIdx.x * blockDim.x + threadIdx.x;
    int stride = gridDim.x * blockDim.x;
    for (; i < E; i += stride) {
        int r = rows[i];
        int p = atomicAdd(&cursor[r], 1);
        ev8[p] = make_int2(cols[i], __float_as_int(vals[i]));
    }
}

// ---------------- GEMM1 (MFMA): h1 = bf16(X) @ bf16(W1) + b1 ----------------
// 128x128 tile, BK=32, 4 waves (2x2), per-wave 64x64 = 4x4 frags of 16x16x32.

__global__ __launch_bounds__(256) void k_gemm1(const float* __restrict__ X,
                                               const float* __restrict__ W,
                                               const float* __restrict__ B,
                                               __hip_bfloat16* __restrict__ H) {
    __shared__ ushort Xs[128 * 32];   // [row][k], 64 B row stride
    __shared__ ushort Ws[128 * 32];   // [n][k]   (W1 tile transposed)
    const int bm = blockIdx.y * 128;
    const int bn = blockIdx.x * 128;
    const int tid = threadIdx.x;
    const int wid = tid >> 6, lane = tid & 63;
    const int wm = wid >> 1, wn = wid & 1;
    const int lr = lane & 15, lg = lane >> 4;

    f32x4 acc[4][4];
    #pragma unroll
    for (int i = 0; i < 4; ++i)
        #pragma unroll
        for (int j = 0; j < 4; ++j)
            acc[i][j] = (f32x4){0.f, 0.f, 0.f, 0.f};

    for (int kt = 0; kt < DI; kt += 32) {
        // stage X tile 128x32 (fp32 -> bf16)
        #pragma unroll
        for (int c = 0; c < 4; ++c) {
            int id = tid + c * 256;
            int row = id >> 3, kc = id & 7;       // kc*4 = k offset
            int gr = bm + row;
            float4 v = {0.f, 0.f, 0.f, 0.f};
            if (gr < NN) v = *(const float4*)(X + (size_t)gr * DI + kt + kc * 4);
            ushort4 p = make_ushort4(f2b(v.x), f2b(v.y), f2b(v.z), f2b(v.w));
            *(ushort4*)&Xs[row * 32 + kc * 4] = p;
        }
        // stage W tile 32x128 transposed -> Ws[n][k]
        #pragma unroll
        for (int c = 0; c < 2; ++c) {
            int id = tid + c * 256;
            int n = id & 127, g = id >> 7;        // g*8 = k offset
            short8 p;
            #pragma unroll
            for (int e = 0; e < 8; ++e)
                p[e] = (short)f2b(W[(size_t)(kt + g * 8 + e) * DH + bn + n]);
            *(short8*)&Ws[n * 32 + g * 8] = p;
        }
        __syncthreads();

        short8 a[4], b[4];
        #pragma unroll
        for (int f = 0; f < 4; ++f) {
            a[f] = *(short8*)&Xs[(wm * 64 + f * 16 + lr) * 32 + lg * 8];
            b[f] = *(short8*)&Ws[(wn * 64 + f * 16 + lr) * 32 + lg * 8];
        }
        #pragma unroll
        for (int i = 0; i < 4; ++i)
            #pragma unroll
            for (int j = 0; j < 4; ++j)
                acc[i][j] = __builtin_amdgcn_mfma_f32_16x16x32_bf16(a[i], b[j], acc[i][j], 0, 0, 0);
        __syncthreads();
    }

    ushort* Hb = (ushort*)H;
    #pragma unroll
    for (int i = 0; i < 4; ++i) {
        int r0 = bm + wm * 64 + i * 16 + lg * 4;
        #pragma unroll
        for (int j = 0; j < 4; ++j) {
            int col = bn + wn * 64 + j * 16 + lr;
            float bias = B[col];
            #pragma unroll
            for (int e = 0; e < 4; ++e) {
                int r = r0 + e;
                if (r < NN) Hb[(size_t)r * DH + col] = f2b(acc[i][j][e] + bias);
            }
        }
    }
}

// ---------------- SpMM1 + ReLU: h1b = relu(A @ h1) ----------------
// one wave per row; lane owns 4 dims (ushort4 = 8B); 4-edge unroll for MLP.

__global__ __launch_bounds__(256) void k_spmm_relu(const int* __restrict__ rp,
                                                   const int2* __restrict__ ev8,
                                                   const __hip_bfloat16* __restrict__ H,
                                                   __hip_bfloat16* __restrict__ O) {
    int r = blockIdx.x * 4 + (threadIdx.x >> 6);
    if (r >= NN) return;
    int lane = threadIdx.x & 63;
    int s = rp[r], e = rp[r + 1];
    const ushort* Hb = (const ushort*)H;
    float a0 = 0.f, a1 = 0.f, a2 = 0.f, a3 = 0.f;

    int i = s;
    for (; i + 4 <= e; i += 4) {
        int2 e0 = ev8[i], e1 = ev8[i + 1], e2 = ev8[i + 2], e3 = ev8[i + 3];
        ushort4 h0 = *((const ushort4*)(Hb + (size_t)e0.x * DH) + lane);
        ushort4 h1 = *((const ushort4*)(Hb + (size_t)e1.x * DH) + lane);
        ushort4 h2 = *((const ushort4*)(Hb + (size_t)e2.x * DH) + lane);
        ushort4 h3 = *((const ushort4*)(Hb + (size_t)e3.x * DH) + lane);
        float v0 = __int_as_float(e0.y), v1 = __int_as_float(e1.y);
        float v2 = __int_as_float(e2.y), v3 = __int_as_float(e3.y);
        a0 += v0 * b2f(h0.x) + v1 * b2f(h1.x) + v2 * b2f(h2.x) + v3 * b2f(h3.x);
        a1 += v0 * b2f(h0.y) + v1 * b2f(h1.y) + v2 * b2f(h2.y) + v3 * b2f(h3.y);
        a2 += v0 * b2f(h0.z) + v1 * b2f(h1.z) + v2 * b2f(h2.z) + v3 * b2f(h3.z);
        a3 += v0 * b2f(h0.w) + v1 * b2f(h1.w) + v2 * b2f(h2.w) + v3 * b2f(h3.w);
    }
    for (; i < e; ++i) {
        int2 ed = ev8[i];
        ushort4 h = *((const ushort4*)(Hb + (size_t)ed.x * DH) + lane);
        float v = __int_as_float(ed.y);
        a0 += v * b2f(h.x); a1 += v * b2f(h.y); a2 += v * b2f(h.z); a3 += v * b2f(h.w);
    }
    ushort4 o = make_ushort4(f2b(fmaxf(a0, 0.f)), f2b(fmaxf(a1, 0.f)),
                             f2b(fmaxf(a2, 0.f)), f2b(fmaxf(a3, 0.f)));
    *((ushort4*)((ushort*)O + (size_t)r * DH) + lane) = o;
}

// ---------------- GEMM2: h2 = h1b @ W2 + b2 (bf16 in/out, fp32 accum) ----------------

__global__ __launch_bounds__(256) void k_gemm2(const __hip_bfloat16* __restrict__ HB,
                                               const float* __restrict__ W,
                                               const float* __restrict__ B,
                                               __hip_bfloat16* __restrict__ H2) {
    __shared__ float hs[4][DH];
    int r0 = blockIdx.x * 4;
    int tid = threadIdx.x;
    for (int i = tid; i < 4 * DH; i += 256) {
        int rr = i >> 8, k = i & 255;
        int r = r0 + rr;
        hs[rr][k] = (r < NN) ? b2f(((const ushort*)HB)[(size_t)r * DH + k]) : 0.f;
    }
    __syncthreads();
    int rr = tid >> 6;
    int j  = tid & 63;
    float acc = B[j];
    #pragma unroll 8
    for (int k = 0; k < DH; ++k) acc += hs[rr][k] * W[k * DO + j];
    int r = r0 + rr;
    if (r < NN) ((ushort*)H2)[(size_t)r * DO + j] = f2b(acc);
}

// ---------------- SpMM2: out = A @ h2 (fp32 out) ----------------
// one wave per row; 16 lanes per edge (ushort4 over 64 dims); 4 edges in flight.

__global__ __launch_bounds__(256) void k_spmm_out(const int* __restrict__ rp,
                                                  const int2* __restrict__ ev8,
                                                  const __hip_bfloat16* __restrict__ H2,
                                                  float* __restrict__ OUT) {
    int r = blockIdx.x * 4 + (threadIdx.x >> 6);
    if (r >= NN) return;
    int lane = threadIdx.x & 63;
    int g = lane >> 4;          // edge slot 0..3
    int q = lane & 15;          // dim quad: dims q*4..q*4+3
    int s = rp[r], e = rp[r + 1];
    const ushort* Hb = (const ushort*)H2;
    float a0 = 0.f, a1 = 0.f, a2 = 0.f, a3 = 0.f;

    for (int i = s + g; i < e; i += 4) {
        int2 ed = ev8[i];
        ushort4 h = *((const ushort4*)(Hb + (size_t)ed.x * DO) + q);
        float v = __int_as_float(ed.y);
        a0 += v * b2f(h.x); a1 += v * b2f(h.y); a2 += v * b2f(h.z); a3 += v * b2f(h.w);
    }
    // reduce across the 4 edge slots (lanes differing in bits 4,5)
    a0 += __shfl_xor(a0, 16); a0 += __shfl_xor(a0, 32);
    a1 += __shfl_xor(a1, 16); a1 += __shfl_xor(a1, 32);
    a2 += __shfl_xor(a2, 16); a2 += __shfl_xor(a2, 32);
    a3 += __shfl_xor(a3, 16); a3 += __shfl_xor(a3, 32);
    if (g == 0) {
        float4 o = make_float4(a0, a1, a2, a3);
        *((float4*)(OUT + (size_t)r * DO) + q) = o;
    }
}

// ---------------- launch ----------------

extern "C" void kernel_launch(void* const* d_in, const int* in_sizes, int n_in,
                              void* d_out, int out_size, void* d_ws, size_t ws_size,
                              hipStream_t stream) {
    const float* x  = (const float*)d_in[0];
    const int*   er = (const int*)d_in[1];
    const int*   ec = (const int*)d_in[2];
    const float* ev = (const float*)d_in[3];
    const float* W1 = (const float*)d_in[4];
    const float* b1 = (const float*)d_in[5];
    const float* W2 = (const float*)d_in[6];
    const float* b2 = (const float*)d_in[7];
    float* out = (float*)d_out;

    char* ws = (char*)d_ws;
    __hip_bfloat16* h1  = (__hip_bfloat16*)ws; ws += (size_t)NN * DH * 2;  // 25.6 MB
    __hip_bfloat16* h1b = (__hip_bfloat16*)ws; ws += (size_t)NN * DH * 2;  // 25.6 MB
    __hip_bfloat16* h2  = (__hip_bfloat16*)ws; ws += (size_t)NN * DO * 2;  //  6.4 MB
    int2*  ev8 = (int2*)ws;  ws += (size_t)NE * 8;                          // 12.8 MB
    int* counts = (int*)ws;  ws += ((size_t)NN * 4 + 255) & ~(size_t)255;
    int* rp     = (int*)ws;  ws += ((size_t)(NN + 1) * 4 + 255) & ~(size_t)255;
    int* cur    = (int*)ws;  ws += ((size_t)NN * 4 + 255) & ~(size_t)255;

    hipMemsetAsync(counts, 0, (size_t)NN * 4, stream);
    k_hist<<<2048, 256, 0, stream>>>(er, counts, NE);
    k_scan<<<1, 1024, 0, stream>>>(counts, rp, cur, NN);
    k_scatter<<<2048, 256, 0, stream>>>(er, ec, ev, cur, ev8, NE);

    dim3 g1(DH / 128, (NN + 127) / 128);
    k_gemm1<<<g1, 256, 0, stream>>>(x, W1, b1, h1);
    k_spmm_relu<<<(NN + 3) / 4, 256, 0, stream>>>(rp, ev8, h1, h1b);
    k_gemm2<<<(NN + 3) / 4, 256, 0, stream>>>(h1b, W2, b2, h2);
    k_spmm_out<<<(NN + 3) / 4, 256, 0, stream>>>(rp, ev8, h2, out);
}

// Round 3
// 522.684 us; speedup vs baseline: 1.9677x; 1.2252x over previous
//
#include <hip/hip_runtime.h>
#include <hip/hip_bf16.h>

constexpr int NN = 50000;
constexpr int NE = 1600000;
constexpr int DI = 512;
constexpr int DH = 256;
constexpr int DO = 64;

constexpr int G1_BLOCKS = ((NN + 127) / 128) * (DH / 128);  // 782
constexpr int SC_BLOCKS = 2048;                             // multiple of 8

typedef __attribute__((ext_vector_type(8))) short short8;
typedef __attribute__((ext_vector_type(4))) float f32x4;

__device__ inline ushort f2b(float f) {          // fp32 -> bf16 bits, RNE
    uint u = __float_as_uint(f);
    u += 0x7fffu + ((u >> 16) & 1u);
    return (ushort)(u >> 16);
}
__device__ inline float b2f(ushort u) {
    return __uint_as_float((uint)u << 16);
}

// ---------------- CSR build ----------------

__global__ void k_hist(const int* __restrict__ rows, int* __restrict__ counts) {
    int i = blockIdx.x * blockDim.x + threadIdx.x;
    int stride = gridDim.x * blockDim.x;
    const int4* r4 = (const int4*)rows;
    for (; i < NE / 4; i += stride) {
        int4 v = r4[i];
        atomicAdd(&counts[v.x], 1);
        atomicAdd(&counts[v.y], 1);
        atomicAdd(&counts[v.z], 1);
        atomicAdd(&counts[v.w], 1);
    }
}

__global__ __launch_bounds__(1024) void k_scan(const int* __restrict__ counts,
                                               int* __restrict__ row_ptr,
                                               int* __restrict__ cursor, int n) {
    const int C = (n + 1023) / 1024;
    int t = threadIdx.x;
    int lo = t * C;
    int hi = min(lo + C, n);
    int s = 0;
    for (int i = lo; i < hi; ++i) s += counts[i];
    __shared__ int buf[1024];
    buf[t] = s;
    __syncthreads();
    for (int off = 1; off < 1024; off <<= 1) {
        int v = (t >= off) ? buf[t - off] : 0;
        __syncthreads();
        buf[t] += v;
        __syncthreads();
    }
    int excl = buf[t] - s;
    for (int i = lo; i < hi; ++i) {
        row_ptr[i] = excl;
        cursor[i]  = excl;
        excl += counts[i];
    }
    if (t == 1023) row_ptr[n] = buf[1023];
}

// ---------------- fat kernel: GEMM1 (MFMA) blocks + XCD-local scatter blocks ----------------

__global__ __launch_bounds__(256) void k_gemm1_scatter(
        const float* __restrict__ X, const float* __restrict__ W,
        const float* __restrict__ B, ushort* __restrict__ H,
        const int* __restrict__ er, const int* __restrict__ ec,
        const float* __restrict__ ev, int* __restrict__ cur,
        int2* __restrict__ ev8) {
    const int bid = blockIdx.x;
    if (bid < G1_BLOCKS) {
        // ---- GEMM1: h1 = bf16(X) @ bf16(W1) + b1, 128x128 tile, BK=32 ----
        __shared__ ushort Xs[128 * 32];
        __shared__ ushort Ws[128 * 32];
        const int bm = (bid >> 1) * 128;
        const int bn = (bid & 1) * 128;
        const int tid = threadIdx.x;
        const int wid = tid >> 6, lane = tid & 63;
        const int wm = wid >> 1, wn = wid & 1;
        const int lr = lane & 15, lg = lane >> 4;

        f32x4 acc[4][4];
        #pragma unroll
        for (int i = 0; i < 4; ++i)
            #pragma unroll
            for (int j = 0; j < 4; ++j)
                acc[i][j] = (f32x4){0.f, 0.f, 0.f, 0.f};

        for (int kt = 0; kt < DI; kt += 32) {
            #pragma unroll
            for (int c = 0; c < 4; ++c) {
                int id = tid + c * 256;
                int row = id >> 3, kc = id & 7;
                int gr = bm + row;
                float4 v = {0.f, 0.f, 0.f, 0.f};
                if (gr < NN) v = *(const float4*)(X + (size_t)gr * DI + kt + kc * 4);
                ushort4 p = make_ushort4(f2b(v.x), f2b(v.y), f2b(v.z), f2b(v.w));
                *(ushort4*)&Xs[row * 32 + kc * 4] = p;
            }
            #pragma unroll
            for (int c = 0; c < 2; ++c) {
                int id = tid + c * 256;
                int n = id & 127, g = id >> 7;
                short8 p;
                #pragma unroll
                for (int e = 0; e < 8; ++e)
                    p[e] = (short)f2b(W[(size_t)(kt + g * 8 + e) * DH + bn + n]);
                *(short8*)&Ws[n * 32 + g * 8] = p;
            }
            __syncthreads();

            short8 a[4], b[4];
            #pragma unroll
            for (int f = 0; f < 4; ++f) {
                a[f] = *(short8*)&Xs[(wm * 64 + f * 16 + lr) * 32 + lg * 8];
                b[f] = *(short8*)&Ws[(wn * 64 + f * 16 + lr) * 32 + lg * 8];
            }
            #pragma unroll
            for (int i = 0; i < 4; ++i)
                #pragma unroll
                for (int j = 0; j < 4; ++j)
                    acc[i][j] = __builtin_amdgcn_mfma_f32_16x16x32_bf16(a[i], b[j], acc[i][j], 0, 0, 0);
            __syncthreads();
        }

        #pragma unroll
        for (int i = 0; i < 4; ++i) {
            int r0 = bm + wm * 64 + i * 16 + lg * 4;
            #pragma unroll
            for (int j = 0; j < 4; ++j) {
                int col = bn + wn * 64 + j * 16 + lr;
                float bias = B[col];
                #pragma unroll
                for (int e = 0; e < 4; ++e) {
                    int r = r0 + e;
                    if (r < NN) H[(size_t)r * DH + col] = f2b(acc[i][j][e] + bias);
                }
            }
        }
    } else {
        // ---- scatter: rows partitioned by physical XCD (blockIdx % 8) so the
        // write target region (~1.6 MB) stays resident in that XCD's 4 MB L2
        // and 8 B scatters coalesce into full-line writebacks. ----
        const int sb = bid - G1_BLOCKS;          // 0..SC_BLOCKS-1 (consecutive)
        const int g  = bid & 7;                  // XCD guess
        const int lb = sb >> 3;                  // 0..255 within group (see note)
        const int lo = g * (NN / 8), hi = lo + (NN / 8);
        const int tid = threadIdx.x;
        const int4* er4 = (const int4*)er;
        const int NQ = NE / 4;
        for (int q = lb * 256 + tid; q < NQ; q += (SC_BLOCKS / 8) * 256) {
            int4 r4 = er4[q];
            int base = q * 4;
            #pragma unroll
            for (int e = 0; e < 4; ++e) {
                int r = (e == 0) ? r4.x : (e == 1) ? r4.y : (e == 2) ? r4.z : r4.w;
                if (r >= lo && r < hi) {
                    int p = atomicAdd(&cur[r], 1);
                    ev8[p] = make_int2(ec[base + e], __float_as_int(ev[base + e]));
                }
            }
        }
    }
}

// ---------------- fused SpMM1 + ReLU + GEMM2 ----------------
// 4 rows per block (1 wave each). Phase 1: gather-accumulate row of A@h1,
// relu, stash fp32 in LDS. Phase 2: x W2 + b2 -> h2 (bf16).

__global__ __launch_bounds__(256) void k_srg(const int* __restrict__ rp,
                                             const int2* __restrict__ ev8,
                                             const ushort* __restrict__ H,
                                             const float* __restrict__ W2,
                                             const float* __restrict__ B2,
                                             ushort* __restrict__ H2) {
    __shared__ float hs[4][DH];
    const int tid = threadIdx.x;
    const int w = tid >> 6, lane = tid & 63;
    const int r = blockIdx.x * 4 + w;

    int s = rp[r], e = rp[r + 1];
    float a0 = 0.f, a1 = 0.f, a2 = 0.f, a3 = 0.f;
    int i = s;
    for (; i + 4 <= e; i += 4) {
        int2 e0 = ev8[i], e1 = ev8[i + 1], e2 = ev8[i + 2], e3 = ev8[i + 3];
        ushort4 h0 = *((const ushort4*)(H + (size_t)e0.x * DH) + lane);
        ushort4 h1 = *((const ushort4*)(H + (size_t)e1.x * DH) + lane);
        ushort4 h2 = *((const ushort4*)(H + (size_t)e2.x * DH) + lane);
        ushort4 h3 = *((const ushort4*)(H + (size_t)e3.x * DH) + lane);
        float v0 = __int_as_float(e0.y), v1 = __int_as_float(e1.y);
        float v2 = __int_as_float(e2.y), v3 = __int_as_float(e3.y);
        a0 += v0 * b2f(h0.x) + v1 * b2f(h1.x) + v2 * b2f(h2.x) + v3 * b2f(h3.x);
        a1 += v0 * b2f(h0.y) + v1 * b2f(h1.y) + v2 * b2f(h2.y) + v3 * b2f(h3.y);
        a2 += v0 * b2f(h0.z) + v1 * b2f(h1.z) + v2 * b2f(h2.z) + v3 * b2f(h3.z);
        a3 += v0 * b2f(h0.w) + v1 * b2f(h1.w) + v2 * b2f(h2.w) + v3 * b2f(h3.w);
    }
    for (; i < e; ++i) {
        int2 ed = ev8[i];
        ushort4 h = *((const ushort4*)(H + (size_t)ed.x * DH) + lane);
        float v = __int_as_float(ed.y);
        a0 += v * b2f(h.x); a1 += v * b2f(h.y); a2 += v * b2f(h.z); a3 += v * b2f(h.w);
    }
    *(float4*)&hs[w][lane * 4] = make_float4(fmaxf(a0, 0.f), fmaxf(a1, 0.f),
                                             fmaxf(a2, 0.f), fmaxf(a3, 0.f));
    __syncthreads();

    const int rr = tid >> 6;
    const int j  = tid & 63;
    float acc = B2[j];
    #pragma unroll 8
    for (int k = 0; k < DH; ++k) acc += hs[rr][k] * W2[k * DO + j];
    H2[(size_t)(blockIdx.x * 4 + rr) * DO + j] = f2b(acc);
}

// ---------------- SpMM2: out = A @ h2 (fp32 out) ----------------

__global__ __launch_bounds__(256) void k_spmm_out(const int* __restrict__ rp,
                                                  const int2* __restrict__ ev8,
                                                  const ushort* __restrict__ H2,
                                                  float* __restrict__ OUT) {
    int r = blockIdx.x * 4 + (threadIdx.x >> 6);
    int lane = threadIdx.x & 63;
    int g = lane >> 4;          // edge slot 0..3
    int q = lane & 15;          // dim quad
    int s = rp[r], e = rp[r + 1];
    float a0 = 0.f, a1 = 0.f, a2 = 0.f, a3 = 0.f;

    for (int i = s + g; i < e; i += 4) {
        int2 ed = ev8[i];
        ushort4 h = *((const ushort4*)(H2 + (size_t)ed.x * DO) + q);
        float v = __int_as_float(ed.y);
        a0 += v * b2f(h.x); a1 += v * b2f(h.y); a2 += v * b2f(h.z); a3 += v * b2f(h.w);
    }
    a0 += __shfl_xor(a0, 16); a0 += __shfl_xor(a0, 32);
    a1 += __shfl_xor(a1, 16); a1 += __shfl_xor(a1, 32);
    a2 += __shfl_xor(a2, 16); a2 += __shfl_xor(a2, 32);
    a3 += __shfl_xor(a3, 16); a3 += __shfl_xor(a3, 32);
    if (g == 0) {
        *((float4*)(OUT + (size_t)r * DO) + q) = make_float4(a0, a1, a2, a3);
    }
}

// ---------------- launch ----------------

extern "C" void kernel_launch(void* const* d_in, const int* in_sizes, int n_in,
                              void* d_out, int out_size, void* d_ws, size_t ws_size,
                              hipStream_t stream) {
    const float* x  = (const float*)d_in[0];
    const int*   er = (const int*)d_in[1];
    const int*   ec = (const int*)d_in[2];
    const float* ev = (const float*)d_in[3];
    const float* W1 = (const float*)d_in[4];
    const float* b1 = (const float*)d_in[5];
    const float* W2 = (const float*)d_in[6];
    const float* b2 = (const float*)d_in[7];
    float* out = (float*)d_out;

    char* ws = (char*)d_ws;
    ushort* h1 = (ushort*)ws; ws += (size_t)NN * DH * 2;                    // 25.6 MB
    ushort* h2 = (ushort*)ws; ws += (size_t)NN * DO * 2;                    //  6.4 MB
    int2*  ev8 = (int2*)ws;   ws += (size_t)NE * 8;                         // 12.8 MB
    int* counts = (int*)ws;   ws += ((size_t)NN * 4 + 255) & ~(size_t)255;
    int* rp     = (int*)ws;   ws += ((size_t)(NN + 1) * 4 + 255) & ~(size_t)255;
    int* cur    = (int*)ws;   ws += ((size_t)NN * 4 + 255) & ~(size_t)255;

    hipMemsetAsync(counts, 0, (size_t)NN * 4, stream);
    k_hist<<<1024, 256, 0, stream>>>(er, counts);
    k_scan<<<1, 1024, 0, stream>>>(counts, rp, cur, NN);
    k_gemm1_scatter<<<G1_BLOCKS + SC_BLOCKS, 256, 0, stream>>>(
        x, W1, b1, h1, er, ec, ev, cur, ev8);
    k_srg<<<NN / 4, 256, 0, stream>>>(rp, ev8, h1, W2, b2, h2);
    k_spmm_out<<<NN / 4, 256, 0, stream>>>(rp, ev8, h2, out);
}